// Round 9
// baseline (225.598 us; speedup 1.0000x reference)
//
#include <hip/hip_runtime.h>
#include <hip/hip_fp16.h>

using half8 = __attribute__((ext_vector_type(8))) _Float16;
using f32x4 = __attribute__((ext_vector_type(4))) float;

#define MAXB 256      // max buckets (LDS sizing); bucket = dst >> 8
#define ECAP 5376     // per-bucket entry capacity (mean 4096, +20 sigma)
#define CHK 32        // LDS staging slots per bucket
#define FLUSH_AT 24   // flush threshold (8 slots headroom per round)
#define BIN_BLOCKS 64

// ---------------- zero bucket counters ----------------

__global__ void zero32(int* __restrict__ p, int n) {
    int i = blockIdx.x * 256 + threadIdx.x;
    if (i < n) p[i] = 0;
}

// ---------------- Pass A: LDS-staged edge binning ----------------
// Entries packed: src (16b) | dlocal (8b) << 16. Flushes are exact-size
// contiguous stores into the bucket's region -> dense lines (~1.3x amp).

__global__ __launch_bounds__(256) void bin_edges_lds(const int* __restrict__ src,
                                                     const int* __restrict__ dst,
                                                     int* __restrict__ bktcnt,
                                                     unsigned int* __restrict__ entries,
                                                     int E, int N) {
    __shared__ unsigned int stage[MAXB][CHK];
    __shared__ int scnt[MAXB];
    int tid = threadIdx.x;
    scnt[tid] = 0;
    __syncthreads();

    int epb = (E + gridDim.x - 1) / gridDim.x;
    int e0 = blockIdx.x * epb;
    int e1 = min(e0 + epb, E);

    for (int base = e0; base < e1; base += 256) {
        int e = base + tid;
        int b = -1;
        unsigned int entry = 0;
        if (e < e1) {
            int s = src[e], d = dst[e];
            if ((unsigned)s < (unsigned)N && (unsigned)d < (unsigned)N) {
                b = d >> 8;
                entry = (unsigned int)s | ((unsigned int)(d & 255) << 16);
            }
        }
        if (b >= 0) {
            int slot = atomicAdd(&scnt[b], 1);
            if (slot < CHK) {
                stage[b][slot] = entry;
            } else {
                // overflow slow path (statistically never; correct if hit)
                int g = atomicAdd(&bktcnt[b], 1);
                if (g < ECAP) entries[(size_t)b * ECAP + g] = entry;
            }
        }
        __syncthreads();
        int c = min(scnt[tid], CHK);
        if (c >= FLUSH_AT) {
            int g = atomicAdd(&bktcnt[tid], c);
            for (int i = 0; i < c; ++i) {
                int idx = g + i;
                if (idx < ECAP) entries[(size_t)tid * ECAP + idx] = stage[tid][i];
            }
            scnt[tid] = 0;
        }
        __syncthreads();
    }
    // final flush
    int c = min(scnt[tid], CHK);
    if (c > 0) {
        int g = atomicAdd(&bktcnt[tid], c);
        for (int i = 0; i < c; ++i) {
            int idx = g + i;
            if (idx < ECAP) entries[(size_t)tid * ECAP + idx] = stage[tid][i];
        }
    }
}

// ---------------- exclusive scan over bucket totals (single pass) ----------------

__global__ void scan_buckets(const int* __restrict__ bktcnt, int* __restrict__ bktbase, int nbkt) {
    __shared__ int s[256];
    int tid = threadIdx.x;
    int v = (tid < nbkt) ? min(bktcnt[tid], ECAP) : 0;
    s[tid] = v;
    __syncthreads();
    for (int off = 1; off < 256; off <<= 1) {
        int t = (tid >= off) ? s[tid - off] : 0;
        __syncthreads();
        s[tid] += t;
        __syncthreads();
    }
    if (tid < nbkt) bktbase[tid] = s[tid] - v;
}

// ---------------- pack W1/W2 into MFMA B-fragment order (fp16, standalone) ----------
// frag (kt,nt): lane l elem j  <->  B[kt*32 + (l>>4)*8 + j][nt*16 + (l&15)]

__global__ void pack_weights(const float* __restrict__ W1, const float* __restrict__ W2,
                             _Float16* __restrict__ W1p, _Float16* __restrict__ W2p) {
    int idx = blockIdx.x * 256 + threadIdx.x;
    if (idx < 32 * 512) {                 // W1: kt 0..3, nt 0..7
        int f = idx >> 9, rem = idx & 511, l = rem >> 3, j = rem & 7;
        int kt = f >> 3, nt = f & 7;
        int k = kt * 32 + (l >> 4) * 8 + j;
        int c = nt * 16 + (l & 15);
        W1p[idx] = (_Float16)W1[k * 128 + c];
    } else if (idx < 32 * 512 + 16 * 512) {  // W2: kt 0..3, nt 0..3
        int i2 = idx - 32 * 512;
        int f = i2 >> 9, rem = i2 & 511, l = rem >> 3, j = rem & 7;
        int kt = f >> 2, nt = f & 3;
        int k = kt * 32 + (l >> 4) * 8 + j;
        int c = nt * 16 + (l & 15);
        W2p[i2] = (_Float16)W2[k * 64 + c];
    }
}

// ---------------- Pass B: per-bucket CSR + fused xd conversion ----------------
// 256 nodes per bucket; entries staged in LDS, per-node count via LDS atomics,
// col_src written to a contiguous per-bucket range; then this bucket's x rows
// converted to dinv-prescaled fp16.

__global__ __launch_bounds__(256) void build_csr_xd(const unsigned int* __restrict__ entries,
                                                    const int* __restrict__ bktcnt,
                                                    const int* __restrict__ bktbase,
                                                    int* __restrict__ rowp, int* __restrict__ cnt,
                                                    float* __restrict__ dinv, int* __restrict__ col_src,
                                                    const float* __restrict__ x,
                                                    __half2* __restrict__ xdh, int N) {
    __shared__ unsigned int ent[ECAP];
    __shared__ int cntL[MAXB], offL[MAXB];
    __shared__ float dinvL[MAXB];
    int b = blockIdx.x;
    int tid = threadIdx.x;
    int tot = min(bktcnt[b], ECAP);
    cntL[tid] = 0;
    __syncthreads();

    const unsigned int* sp = entries + (size_t)b * ECAP;
    for (int i = tid; i < tot; i += 256) {
        unsigned int v = sp[i];
        ent[i] = v;
        atomicAdd(&cntL[(v >> 16) & 255], 1);
    }
    __syncthreads();
    if (tid == 0) {
        int a = 0;
        for (int i = 0; i < MAXB; ++i) { offL[i] = a; a += cntL[i]; }
    }
    __syncthreads();

    int base = bktbase[b];
    int node0 = b << 8;
    int node = node0 + tid;
    int c = cntL[tid];
    float dv = rsqrtf((float)(c + 1));        // +1 self-loop
    dinvL[tid] = dv;
    if (node < N) {
        rowp[node] = base + offL[tid];
        cnt[node]  = c;
        dinv[node] = dv;
    }
    cntL[tid] = offL[tid];                    // reuse as fill counters
    __syncthreads();
    for (int i = tid; i < tot; i += 256) {
        unsigned int v = ent[i];
        int slot = atomicAdd(&cntL[(v >> 16) & 255], 1);
        col_src[base + slot] = (int)(v & 0xFFFFu);
    }

    // fused: xdh[row] = fp16(dinv[row] * x[row]) for this bucket's 256 rows
    for (int i = tid; i < 256 * 64; i += 256) {
        int r = i >> 6;
        int row = node0 + r;
        if (row < N) {
            float di = dinvL[r];
            float2 xv = *(const float2*)&x[(size_t)row * 128 + (size_t)(i & 63) * 2];
            xdh[(size_t)row * 64 + (i & 63)] = __float22half2_rn(make_float2(di * xv.x, di * xv.y));
        }
    }
}

// ---------------- layer-1 gather: ax[i] = dinv_i * (xd_i + sum_p xd_{s_p}) ----------------

__global__ void agg_x128_h(const __half2* __restrict__ x2, const int* __restrict__ rowp,
                           const int* __restrict__ cnt, const int* __restrict__ col,
                           const float* __restrict__ dinv, __half2* __restrict__ out2, int n) {
    int node = blockIdx.x * 4 + (threadIdx.x >> 6);
    if (node >= n) return;
    int lane = threadIdx.x & 63;
    float2 self = __half22float2(x2[(size_t)node * 64 + lane]);
    float ax0 = self.x, ay0 = self.y;
    float ax1 = 0.f, ay1 = 0.f, ax2 = 0.f, ay2 = 0.f, ax3 = 0.f, ay3 = 0.f;
    float ax4 = 0.f, ay4 = 0.f, ax5 = 0.f, ay5 = 0.f, ax6 = 0.f, ay6 = 0.f, ax7 = 0.f, ay7 = 0.f;
    int p = rowp[node];
    int deg = cnt[node];
    int k = 0;
    for (; k + 8 <= deg; k += 8) {
        int s0 = col[p + k + 0], s1 = col[p + k + 1], s2 = col[p + k + 2], s3 = col[p + k + 3];
        int s4 = col[p + k + 4], s5 = col[p + k + 5], s6 = col[p + k + 6], s7 = col[p + k + 7];
        float2 v0 = __half22float2(x2[(size_t)s0 * 64 + lane]);
        float2 v1 = __half22float2(x2[(size_t)s1 * 64 + lane]);
        float2 v2 = __half22float2(x2[(size_t)s2 * 64 + lane]);
        float2 v3 = __half22float2(x2[(size_t)s3 * 64 + lane]);
        float2 v4 = __half22float2(x2[(size_t)s4 * 64 + lane]);
        float2 v5 = __half22float2(x2[(size_t)s5 * 64 + lane]);
        float2 v6 = __half22float2(x2[(size_t)s6 * 64 + lane]);
        float2 v7 = __half22float2(x2[(size_t)s7 * 64 + lane]);
        ax0 += v0.x; ay0 += v0.y;  ax1 += v1.x; ay1 += v1.y;
        ax2 += v2.x; ay2 += v2.y;  ax3 += v3.x; ay3 += v3.y;
        ax4 += v4.x; ay4 += v4.y;  ax5 += v5.x; ay5 += v5.y;
        ax6 += v6.x; ay6 += v6.y;  ax7 += v7.x; ay7 += v7.y;
    }
    for (; k < deg; ++k) {
        float2 v = __half22float2(x2[(size_t)col[p + k] * 64 + lane]);
        ax0 += v.x; ay0 += v.y;
    }
    float ax = ((ax0 + ax1) + (ax2 + ax3)) + ((ax4 + ax5) + (ax6 + ax7));
    float ay = ((ay0 + ay1) + (ay2 + ay3)) + ((ay4 + ay5) + (ay6 + ay7));
    float di = dinv[node];
    out2[(size_t)node * 64 + lane] = __float22half2_rn(make_float2(di * ax, di * ay));
}

// ---------------- fused MLP on MFMA: yh = dinv * (relu(AX@W1+b1) @ W2) ----------------
// 4 waves/block, each wave owns 16 rows. A-frags from global; h via per-wave LDS tile.
// Fragment layouts (v_mfma_f32_16x16x32_f16):
//   A: lane l elem j <-> A[l&15][(l>>4)*8+j]
//   B: packed by pack_weights
//   C/D: lane l reg r <-> D[(l>>4)*4+r][l&15]   (m89-verified)

__global__ __launch_bounds__(256) void mlp_mfma(const _Float16* __restrict__ axh,
                                                const _Float16* __restrict__ W1p,
                                                const float* __restrict__ b1,
                                                const _Float16* __restrict__ W2p,
                                                const float* __restrict__ dinv,
                                                _Float16* __restrict__ yh, int M) {
    __shared__ _Float16 sh[4][16][136];   // per-wave h tile, stride 136 halves (272 B)
    int t = threadIdx.x;
    int w = t >> 6, l = t & 63;
    int rlo = l & 15, khi = l >> 4;
    int row0 = blockIdx.x * 64 + w * 16;

    // A fragments (16 rows x K=128) straight from global
    half8 a[4];
    int arow = row0 + rlo;
    const _Float16* arp = axh + (size_t)arow * 128 + khi * 8;
#pragma unroll
    for (int kt = 0; kt < 4; ++kt) {
        half8 v = {};
        if (arow < M) v = *(const half8*)(arp + kt * 32);
        a[kt] = v;
    }

    // GEMM1: 16x128 out per wave = 8 col-tiles
    f32x4 acc[8];
#pragma unroll
    for (int nt = 0; nt < 8; ++nt) acc[nt] = (f32x4){0.f, 0.f, 0.f, 0.f};
#pragma unroll
    for (int nt = 0; nt < 8; ++nt) {
#pragma unroll
        for (int kt = 0; kt < 4; ++kt) {
            half8 b = *(const half8*)&W1p[(size_t)((kt * 8 + nt) * 64 + l) * 8];
            acc[nt] = __builtin_amdgcn_mfma_f32_16x16x32_f16(a[kt], b, acc[nt], 0, 0, 0);
        }
    }

    // h = relu(acc + b1) -> LDS (fp16), then re-read as A-fragments
#pragma unroll
    for (int nt = 0; nt < 8; ++nt) {
        float bb = b1[nt * 16 + rlo];
#pragma unroll
        for (int r = 0; r < 4; ++r) {
            sh[w][khi * 4 + r][nt * 16 + rlo] = (_Float16)fmaxf(acc[nt][r] + bb, 0.f);
        }
    }
    __syncthreads();

    half8 a2[4];
#pragma unroll
    for (int kt = 0; kt < 4; ++kt)
        a2[kt] = *(const half8*)&sh[w][rlo][kt * 32 + khi * 8];

    // GEMM2: 16x64 out per wave = 4 col-tiles
    f32x4 acc2[4];
#pragma unroll
    for (int nt = 0; nt < 4; ++nt) acc2[nt] = (f32x4){0.f, 0.f, 0.f, 0.f};
#pragma unroll
    for (int nt = 0; nt < 4; ++nt) {
#pragma unroll
        for (int kt = 0; kt < 4; ++kt) {
            half8 b = *(const half8*)&W2p[(size_t)((kt * 4 + nt) * 64 + l) * 8];
            acc2[nt] = __builtin_amdgcn_mfma_f32_16x16x32_f16(a2[kt], b, acc2[nt], 0, 0, 0);
        }
    }

    // epilogue: y = acc2 * dinv[row], fp16 store
#pragma unroll
    for (int r = 0; r < 4; ++r) {
        int row = row0 + khi * 4 + r;
        if (row < M) {
            float dn = dinv[row];
#pragma unroll
            for (int nt = 0; nt < 4; ++nt)
                yh[(size_t)row * 64 + nt * 16 + rlo] = (_Float16)(acc2[nt][r] * dn);
        }
    }
}

// ---------------- layer-2 gather: out = relu(b2 + dinv_i * (y_i + sum_p y_{s_p})) ----------------

__global__ void agg_y64_h(const __half* __restrict__ y, const int* __restrict__ rowp,
                          const int* __restrict__ cnt, const int* __restrict__ col,
                          const float* __restrict__ dinv, const float* __restrict__ bias,
                          float* __restrict__ out, int n) {
    int node = blockIdx.x * 4 + (threadIdx.x >> 6);
    if (node >= n) return;
    int lane = threadIdx.x & 63;
    const __half* yc = y + lane;
    float a0 = __half2float(yc[(size_t)node * 64]);
    float a1 = 0.f, a2 = 0.f, a3 = 0.f, a4 = 0.f, a5 = 0.f, a6 = 0.f, a7 = 0.f;
    int p = rowp[node];
    int deg = cnt[node];
    int k = 0;
    for (; k + 8 <= deg; k += 8) {
        int s0 = col[p + k + 0], s1 = col[p + k + 1], s2 = col[p + k + 2], s3 = col[p + k + 3];
        int s4 = col[p + k + 4], s5 = col[p + k + 5], s6 = col[p + k + 6], s7 = col[p + k + 7];
        a0 += __half2float(yc[(size_t)s0 * 64]);
        a1 += __half2float(yc[(size_t)s1 * 64]);
        a2 += __half2float(yc[(size_t)s2 * 64]);
        a3 += __half2float(yc[(size_t)s3 * 64]);
        a4 += __half2float(yc[(size_t)s4 * 64]);
        a5 += __half2float(yc[(size_t)s5 * 64]);
        a6 += __half2float(yc[(size_t)s6 * 64]);
        a7 += __half2float(yc[(size_t)s7 * 64]);
    }
    for (; k < deg; ++k) {
        a0 += __half2float(yc[(size_t)col[p + k] * 64]);
    }
    float a = ((a0 + a1) + (a2 + a3)) + ((a4 + a5) + (a6 + a7));
    out[(size_t)node * 64 + lane] = fmaxf(bias[lane] + dinv[node] * a, 0.f);
}

// ---------------- launch ----------------

extern "C" void kernel_launch(void* const* d_in, const int* in_sizes, int n_in,
                              void* d_out, int out_size, void* d_ws, size_t ws_size,
                              hipStream_t stream) {
    const float* x  = (const float*)d_in[0];
    const int*   ei = (const int*)d_in[1];          // integer inputs arrive as int32
    const float* W1 = (const float*)d_in[2];
    const float* b1 = (const float*)d_in[3];
    const float* W2 = (const float*)d_in[4];
    const float* b2 = (const float*)d_in[5];
    float* out = (float*)d_out;

    const int N = in_sizes[0] / 128;
    const int E = in_sizes[1] / 2;
    const int nbkt = (N + 255) >> 8;                // 196 buckets of 256 nodes
    const int* src = ei;
    const int* dst = ei + E;

    char* ws = (char*)d_ws;
    size_t off = 0;
    auto alloc = [&](size_t bytes) {
        void* p = ws + off;
        off += (bytes + 255) & ~(size_t)255;
        return p;
    };
    int*          cnt     = (int*)         alloc((size_t)N * 4);
    float*        dinv    = (float*)       alloc((size_t)N * 4);
    int*          rowp    = (int*)         alloc((size_t)N * 4);
    int*          bktcnt  = (int*)         alloc((size_t)MAXB * 4);
    int*          bktbase = (int*)         alloc((size_t)MAXB * 4);
    unsigned int* entries = (unsigned int*)alloc((size_t)nbkt * ECAP * 4);
    int*          col_src = (int*)         alloc((size_t)E * 4);
    __half2*      xdh     = (__half2*)     alloc((size_t)N * 128 * 2);   // dinv-scaled x, fp16
    __half2*      axh     = (__half2*)     alloc((size_t)N * 128 * 2);   // aggregated AX, fp16
    __half2*      yh      = (__half2*)     alloc((size_t)N * 64 * 2);    // dinv-scaled h@W2, fp16
    _Float16*     W1p     = (_Float16*)    alloc((size_t)32 * 512 * 2);  // MFMA-packed W1
    _Float16*     W2p     = (_Float16*)    alloc((size_t)16 * 512 * 2);  // MFMA-packed W2
    // total ~= 40 MB

    zero32<<<1, 256, 0, stream>>>(bktcnt, MAXB);
    bin_edges_lds<<<BIN_BLOCKS, 256, 0, stream>>>(src, dst, bktcnt, entries, E, N);
    scan_buckets<<<1, 256, 0, stream>>>(bktcnt, bktbase, nbkt);
    pack_weights<<<96, 256, 0, stream>>>(W1, W2, W1p, W2p);
    build_csr_xd<<<nbkt, 256, 0, stream>>>(entries, bktcnt, bktbase, rowp, cnt, dinv, col_src,
                                           x, xdh, N);

    agg_x128_h<<<(N + 3) / 4, 256, 0, stream>>>(xdh, rowp, cnt, col_src, dinv, axh, N);
    mlp_mfma<<<(N + 63) / 64, 256, 0, stream>>>((const _Float16*)axh, W1p, b1, W2p, dinv,
                                                (_Float16*)yh, N);
    agg_y64_h<<<(N + 3) / 4, 256, 0, stream>>>((const __half*)yh, rowp, cnt, col_src, dinv, b2, out, N);
}

// Round 10
// 141.160 us; speedup vs baseline: 1.5982x; 1.5982x over previous
//
#include <hip/hip_runtime.h>
#include <hip/hip_fp16.h>

using half8 = __attribute__((ext_vector_type(8))) _Float16;
using f32x4 = __attribute__((ext_vector_type(4))) float;

#define MAXB 256      // max buckets (LDS sizing); bucket = dst >> 8
#define ECAP 5376     // per-bucket entry capacity (mean 4096, +20 sigma)
#define EPB  3200     // edges per bin block

// ---------------- zero bucket counters ----------------

__global__ void zero32(int* __restrict__ p, int n) {
    int i = blockIdx.x * 256 + threadIdx.x;
    if (i < n) p[i] = 0;
}

// ---------------- Pass A: per-block counting-sort binning ----------------
// One block owns <=3200 contiguous edges. Barrier-free LDS staging (direct
// indexed), per-bucket LDS counts, ONE global reservation per bucket per
// block, then placement with per-bucket fill counters. Per-(bucket,block)
// output runs are ~13 contiguous entries -> ~2x write amp (vs 9x scattered).

__global__ __launch_bounds__(256) void bin_sort(const int* __restrict__ src,
                                                const int* __restrict__ dst,
                                                int* __restrict__ bktcnt,
                                                unsigned int* __restrict__ entries,
                                                int E, int N) {
    __shared__ unsigned int ebuf[EPB];
    __shared__ unsigned char bbuf[EPB];
    __shared__ int cntL[MAXB], fillL[MAXB], baseL[MAXB];
    int tid = threadIdx.x;
    cntL[tid] = 0;
    __syncthreads();

    int e0 = blockIdx.x * EPB;
    int e1 = min(e0 + EPB, E);
    int m = e1 - e0;

    // pass 1: stage + count (no barriers inside)
    for (int i = tid; i < m; i += 256) {
        int e = e0 + i;
        int s = src[e], d = dst[e];
        int b = 0;
        unsigned int entry = 0xFFFFFFFFu;
        if ((unsigned)s < (unsigned)N && (unsigned)d < (unsigned)N) {
            b = d >> 8;
            entry = (unsigned int)s | ((unsigned int)(d & 255) << 16);
            atomicAdd(&cntL[b], 1);
        }
        ebuf[i] = entry;
        bbuf[i] = (unsigned char)b;
    }
    __syncthreads();

    // single reservation phase: one global atomic per non-empty bucket
    int c = cntL[tid];
    if (c > 0) baseL[tid] = atomicAdd(&bktcnt[tid], c);
    fillL[tid] = 0;
    __syncthreads();

    // pass 2: placement (same-bucket lanes -> consecutive addresses)
    for (int i = tid; i < m; i += 256) {
        unsigned int entry = ebuf[i];
        if (entry == 0xFFFFFFFFu) continue;
        int b = bbuf[i];
        int pos = atomicAdd(&fillL[b], 1);
        int idx = baseL[b] + pos;
        if (idx < ECAP) entries[(size_t)b * ECAP + idx] = entry;
    }
}

// ---------------- exclusive scan over bucket totals (single pass) ----------------

__global__ void scan_buckets(const int* __restrict__ bktcnt, int* __restrict__ bktbase, int nbkt) {
    __shared__ int s[256];
    int tid = threadIdx.x;
    int v = (tid < nbkt) ? min(bktcnt[tid], ECAP) : 0;
    s[tid] = v;
    __syncthreads();
    for (int off = 1; off < 256; off <<= 1) {
        int t = (tid >= off) ? s[tid - off] : 0;
        __syncthreads();
        s[tid] += t;
        __syncthreads();
    }
    if (tid < nbkt) bktbase[tid] = s[tid] - v;
}

// ---------------- pack W1/W2 into MFMA B-fragment order (fp16, standalone) ----------
// frag (kt,nt): lane l elem j  <->  B[kt*32 + (l>>4)*8 + j][nt*16 + (l&15)]

__global__ void pack_weights(const float* __restrict__ W1, const float* __restrict__ W2,
                             _Float16* __restrict__ W1p, _Float16* __restrict__ W2p) {
    int idx = blockIdx.x * 256 + threadIdx.x;
    if (idx < 32 * 512) {                 // W1: kt 0..3, nt 0..7
        int f = idx >> 9, rem = idx & 511, l = rem >> 3, j = rem & 7;
        int kt = f >> 3, nt = f & 7;
        int k = kt * 32 + (l >> 4) * 8 + j;
        int c = nt * 16 + (l & 15);
        W1p[idx] = (_Float16)W1[k * 128 + c];
    } else if (idx < 32 * 512 + 16 * 512) {  // W2: kt 0..3, nt 0..3
        int i2 = idx - 32 * 512;
        int f = i2 >> 9, rem = i2 & 511, l = rem >> 3, j = rem & 7;
        int kt = f >> 2, nt = f & 3;
        int k = kt * 32 + (l >> 4) * 8 + j;
        int c = nt * 16 + (l & 15);
        W2p[i2] = (_Float16)W2[k * 64 + c];
    }
}

// ---------------- Pass B: per-bucket CSR + fused xd conversion ----------------
// 256 nodes per bucket; entries staged in LDS, per-node count via LDS atomics,
// col_src written to a contiguous per-bucket range; then this bucket's x rows
// converted to dinv-prescaled fp16.

__global__ __launch_bounds__(256) void build_csr_xd(const unsigned int* __restrict__ entries,
                                                    const int* __restrict__ bktcnt,
                                                    const int* __restrict__ bktbase,
                                                    int* __restrict__ rowp, int* __restrict__ cnt,
                                                    float* __restrict__ dinv, int* __restrict__ col_src,
                                                    const float* __restrict__ x,
                                                    __half2* __restrict__ xdh, int N) {
    __shared__ unsigned int ent[ECAP];
    __shared__ int cntL[MAXB], offL[MAXB];
    __shared__ float dinvL[MAXB];
    int b = blockIdx.x;
    int tid = threadIdx.x;
    int tot = min(bktcnt[b], ECAP);
    cntL[tid] = 0;
    __syncthreads();

    const unsigned int* sp = entries + (size_t)b * ECAP;
    for (int i = tid; i < tot; i += 256) {
        unsigned int v = sp[i];
        ent[i] = v;
        atomicAdd(&cntL[(v >> 16) & 255], 1);
    }
    __syncthreads();
    if (tid == 0) {
        int a = 0;
        for (int i = 0; i < MAXB; ++i) { offL[i] = a; a += cntL[i]; }
    }
    __syncthreads();

    int base = bktbase[b];
    int node0 = b << 8;
    int node = node0 + tid;
    int c = cntL[tid];
    float dv = rsqrtf((float)(c + 1));        // +1 self-loop
    dinvL[tid] = dv;
    if (node < N) {
        rowp[node] = base + offL[tid];
        cnt[node]  = c;
        dinv[node] = dv;
    }
    cntL[tid] = offL[tid];                    // reuse as fill counters
    __syncthreads();
    for (int i = tid; i < tot; i += 256) {
        unsigned int v = ent[i];
        int slot = atomicAdd(&cntL[(v >> 16) & 255], 1);
        col_src[base + slot] = (int)(v & 0xFFFFu);
    }

    // fused: xdh[row] = fp16(dinv[row] * x[row]) for this bucket's 256 rows
    for (int i = tid; i < 256 * 64; i += 256) {
        int r = i >> 6;
        int row = node0 + r;
        if (row < N) {
            float di = dinvL[r];
            float2 xv = *(const float2*)&x[(size_t)row * 128 + (size_t)(i & 63) * 2];
            xdh[(size_t)row * 64 + (i & 63)] = __float22half2_rn(make_float2(di * xv.x, di * xv.y));
        }
    }
}

// ---------------- layer-1 gather: ax[i] = dinv_i * (xd_i + sum_p xd_{s_p}) ----------------

__global__ void agg_x128_h(const __half2* __restrict__ x2, const int* __restrict__ rowp,
                           const int* __restrict__ cnt, const int* __restrict__ col,
                           const float* __restrict__ dinv, __half2* __restrict__ out2, int n) {
    int node = blockIdx.x * 4 + (threadIdx.x >> 6);
    if (node >= n) return;
    int lane = threadIdx.x & 63;
    float2 self = __half22float2(x2[(size_t)node * 64 + lane]);
    float ax0 = self.x, ay0 = self.y;
    float ax1 = 0.f, ay1 = 0.f, ax2 = 0.f, ay2 = 0.f, ax3 = 0.f, ay3 = 0.f;
    float ax4 = 0.f, ay4 = 0.f, ax5 = 0.f, ay5 = 0.f, ax6 = 0.f, ay6 = 0.f, ax7 = 0.f, ay7 = 0.f;
    int p = rowp[node];
    int deg = cnt[node];
    int k = 0;
    for (; k + 8 <= deg; k += 8) {
        int s0 = col[p + k + 0], s1 = col[p + k + 1], s2 = col[p + k + 2], s3 = col[p + k + 3];
        int s4 = col[p + k + 4], s5 = col[p + k + 5], s6 = col[p + k + 6], s7 = col[p + k + 7];
        float2 v0 = __half22float2(x2[(size_t)s0 * 64 + lane]);
        float2 v1 = __half22float2(x2[(size_t)s1 * 64 + lane]);
        float2 v2 = __half22float2(x2[(size_t)s2 * 64 + lane]);
        float2 v3 = __half22float2(x2[(size_t)s3 * 64 + lane]);
        float2 v4 = __half22float2(x2[(size_t)s4 * 64 + lane]);
        float2 v5 = __half22float2(x2[(size_t)s5 * 64 + lane]);
        float2 v6 = __half22float2(x2[(size_t)s6 * 64 + lane]);
        float2 v7 = __half22float2(x2[(size_t)s7 * 64 + lane]);
        ax0 += v0.x; ay0 += v0.y;  ax1 += v1.x; ay1 += v1.y;
        ax2 += v2.x; ay2 += v2.y;  ax3 += v3.x; ay3 += v3.y;
        ax4 += v4.x; ay4 += v4.y;  ax5 += v5.x; ay5 += v5.y;
        ax6 += v6.x; ay6 += v6.y;  ax7 += v7.x; ay7 += v7.y;
    }
    for (; k < deg; ++k) {
        float2 v = __half22float2(x2[(size_t)col[p + k] * 64 + lane]);
        ax0 += v.x; ay0 += v.y;
    }
    float ax = ((ax0 + ax1) + (ax2 + ax3)) + ((ax4 + ax5) + (ax6 + ax7));
    float ay = ((ay0 + ay1) + (ay2 + ay3)) + ((ay4 + ay5) + (ay6 + ay7));
    float di = dinv[node];
    out2[(size_t)node * 64 + lane] = __float22half2_rn(make_float2(di * ax, di * ay));
}

// ---------------- fused MLP on MFMA: yh = dinv * (relu(AX@W1+b1) @ W2) ----------------
// 4 waves/block, each wave owns 16 rows. A-frags from global; h via per-wave LDS tile.
// Fragment layouts (v_mfma_f32_16x16x32_f16):
//   A: lane l elem j <-> A[l&15][(l>>4)*8+j]
//   B: packed by pack_weights
//   C/D: lane l reg r <-> D[(l>>4)*4+r][l&15]   (m89-verified)

__global__ __launch_bounds__(256) void mlp_mfma(const _Float16* __restrict__ axh,
                                                const _Float16* __restrict__ W1p,
                                                const float* __restrict__ b1,
                                                const _Float16* __restrict__ W2p,
                                                const float* __restrict__ dinv,
                                                _Float16* __restrict__ yh, int M) {
    __shared__ _Float16 sh[4][16][136];   // per-wave h tile, stride 136 halves (272 B)
    int t = threadIdx.x;
    int w = t >> 6, l = t & 63;
    int rlo = l & 15, khi = l >> 4;
    int row0 = blockIdx.x * 64 + w * 16;

    // A fragments (16 rows x K=128) straight from global
    half8 a[4];
    int arow = row0 + rlo;
    const _Float16* arp = axh + (size_t)arow * 128 + khi * 8;
#pragma unroll
    for (int kt = 0; kt < 4; ++kt) {
        half8 v = {};
        if (arow < M) v = *(const half8*)(arp + kt * 32);
        a[kt] = v;
    }

    // GEMM1: 16x128 out per wave = 8 col-tiles
    f32x4 acc[8];
#pragma unroll
    for (int nt = 0; nt < 8; ++nt) acc[nt] = (f32x4){0.f, 0.f, 0.f, 0.f};
#pragma unroll
    for (int nt = 0; nt < 8; ++nt) {
#pragma unroll
        for (int kt = 0; kt < 4; ++kt) {
            half8 b = *(const half8*)&W1p[(size_t)((kt * 8 + nt) * 64 + l) * 8];
            acc[nt] = __builtin_amdgcn_mfma_f32_16x16x32_f16(a[kt], b, acc[nt], 0, 0, 0);
        }
    }

    // h = relu(acc + b1) -> LDS (fp16), then re-read as A-fragments
#pragma unroll
    for (int nt = 0; nt < 8; ++nt) {
        float bb = b1[nt * 16 + rlo];
#pragma unroll
        for (int r = 0; r < 4; ++r) {
            sh[w][khi * 4 + r][nt * 16 + rlo] = (_Float16)fmaxf(acc[nt][r] + bb, 0.f);
        }
    }
    __syncthreads();

    half8 a2[4];
#pragma unroll
    for (int kt = 0; kt < 4; ++kt)
        a2[kt] = *(const half8*)&sh[w][rlo][kt * 32 + khi * 8];

    // GEMM2: 16x64 out per wave = 4 col-tiles
    f32x4 acc2[4];
#pragma unroll
    for (int nt = 0; nt < 4; ++nt) acc2[nt] = (f32x4){0.f, 0.f, 0.f, 0.f};
#pragma unroll
    for (int nt = 0; nt < 4; ++nt) {
#pragma unroll
        for (int kt = 0; kt < 4; ++kt) {
            half8 b = *(const half8*)&W2p[(size_t)((kt * 4 + nt) * 64 + l) * 8];
            acc2[nt] = __builtin_amdgcn_mfma_f32_16x16x32_f16(a2[kt], b, acc2[nt], 0, 0, 0);
        }
    }

    // epilogue: y = acc2 * dinv[row], fp16 store
#pragma unroll
    for (int r = 0; r < 4; ++r) {
        int row = row0 + khi * 4 + r;
        if (row < M) {
            float dn = dinv[row];
#pragma unroll
            for (int nt = 0; nt < 4; ++nt)
                yh[(size_t)row * 64 + nt * 16 + rlo] = (_Float16)(acc2[nt][r] * dn);
        }
    }
}

// ---------------- layer-2 gather: out = relu(b2 + dinv_i * (y_i + sum_p y_{s_p})) ----------------

__global__ void agg_y64_h(const __half* __restrict__ y, const int* __restrict__ rowp,
                          const int* __restrict__ cnt, const int* __restrict__ col,
                          const float* __restrict__ dinv, const float* __restrict__ bias,
                          float* __restrict__ out, int n) {
    int node = blockIdx.x * 4 + (threadIdx.x >> 6);
    if (node >= n) return;
    int lane = threadIdx.x & 63;
    const __half* yc = y + lane;
    float a0 = __half2float(yc[(size_t)node * 64]);
    float a1 = 0.f, a2 = 0.f, a3 = 0.f, a4 = 0.f, a5 = 0.f, a6 = 0.f, a7 = 0.f;
    int p = rowp[node];
    int deg = cnt[node];
    int k = 0;
    for (; k + 8 <= deg; k += 8) {
        int s0 = col[p + k + 0], s1 = col[p + k + 1], s2 = col[p + k + 2], s3 = col[p + k + 3];
        int s4 = col[p + k + 4], s5 = col[p + k + 5], s6 = col[p + k + 6], s7 = col[p + k + 7];
        a0 += __half2float(yc[(size_t)s0 * 64]);
        a1 += __half2float(yc[(size_t)s1 * 64]);
        a2 += __half2float(yc[(size_t)s2 * 64]);
        a3 += __half2float(yc[(size_t)s3 * 64]);
        a4 += __half2float(yc[(size_t)s4 * 64]);
        a5 += __half2float(yc[(size_t)s5 * 64]);
        a6 += __half2float(yc[(size_t)s6 * 64]);
        a7 += __half2float(yc[(size_t)s7 * 64]);
    }
    for (; k < deg; ++k) {
        a0 += __half2float(yc[(size_t)col[p + k] * 64]);
    }
    float a = ((a0 + a1) + (a2 + a3)) + ((a4 + a5) + (a6 + a7));
    out[(size_t)node * 64 + lane] = fmaxf(bias[lane] + dinv[node] * a, 0.f);
}

// ---------------- launch ----------------

extern "C" void kernel_launch(void* const* d_in, const int* in_sizes, int n_in,
                              void* d_out, int out_size, void* d_ws, size_t ws_size,
                              hipStream_t stream) {
    const float* x  = (const float*)d_in[0];
    const int*   ei = (const int*)d_in[1];          // integer inputs arrive as int32
    const float* W1 = (const float*)d_in[2];
    const float* b1 = (const float*)d_in[3];
    const float* W2 = (const float*)d_in[4];
    const float* b2 = (const float*)d_in[5];
    float* out = (float*)d_out;

    const int N = in_sizes[0] / 128;
    const int E = in_sizes[1] / 2;
    const int nbkt = (N + 255) >> 8;                // 196 buckets of 256 nodes
    const int* src = ei;
    const int* dst = ei + E;

    char* ws = (char*)d_ws;
    size_t off = 0;
    auto alloc = [&](size_t bytes) {
        void* p = ws + off;
        off += (bytes + 255) & ~(size_t)255;
        return p;
    };
    int*          cnt     = (int*)         alloc((size_t)N * 4);
    float*        dinv    = (float*)       alloc((size_t)N * 4);
    int*          rowp    = (int*)         alloc((size_t)N * 4);
    int*          bktcnt  = (int*)         alloc((size_t)MAXB * 4);
    int*          bktbase = (int*)         alloc((size_t)MAXB * 4);
    unsigned int* entries = (unsigned int*)alloc((size_t)nbkt * ECAP * 4);
    int*          col_src = (int*)         alloc((size_t)E * 4);
    __half2*      xdh     = (__half2*)     alloc((size_t)N * 128 * 2);   // dinv-scaled x, fp16
    __half2*      axh     = (__half2*)     alloc((size_t)N * 128 * 2);   // aggregated AX, fp16
    __half2*      yh      = (__half2*)     alloc((size_t)N * 64 * 2);    // dinv-scaled h@W2, fp16
    _Float16*     W1p     = (_Float16*)    alloc((size_t)32 * 512 * 2);  // MFMA-packed W1
    _Float16*     W2p     = (_Float16*)    alloc((size_t)16 * 512 * 2);  // MFMA-packed W2
    // total ~= 40 MB

    const int binBlocks = (E + EPB - 1) / EPB;      // 250 for E=800k

    zero32<<<1, 256, 0, stream>>>(bktcnt, MAXB);
    bin_sort<<<binBlocks, 256, 0, stream>>>(src, dst, bktcnt, entries, E, N);
    scan_buckets<<<1, 256, 0, stream>>>(bktcnt, bktbase, nbkt);
    pack_weights<<<96, 256, 0, stream>>>(W1, W2, W1p, W2p);
    build_csr_xd<<<nbkt, 256, 0, stream>>>(entries, bktcnt, bktbase, rowp, cnt, dinv, col_src,
                                           x, xdh, N);

    agg_x128_h<<<(N + 3) / 4, 256, 0, stream>>>(xdh, rowp, cnt, col_src, dinv, axh, N);
    mlp_mfma<<<(N + 63) / 64, 256, 0, stream>>>((const _Float16*)axh, W1p, b1, W2p, dinv,
                                                (_Float16*)yh, N);
    agg_y64_h<<<(N + 3) / 4, 256, 0, stream>>>((const __half*)yh, rowp, cnt, col_src, dinv, b2, out, N);
}